// Round 4
// baseline (1349.506 us; speedup 1.0000x reference)
//
#include <hip/hip_runtime.h>
#include <cstdint>

// LSTM: B=1024, T=336, I=64, H=256, gates 4H=1024, K = I+H = 320.
// 32 batch-groups x 8 member-WGs = 256 WGs (1/CU), persistent over all T.
// R4: gate-row remap r16 = 4*col + gate, so the MFMA D-tile hands each lane
// all 4 gates of one (col,batch) cell in regs 0..3 -> cell fully in
// registers, no gates LDS round-trip, no second barrier, bias as acc-init.
// Waves own 32 rows x 16 batch (B-reads halved). v_lds double-buffered ->
// ONE __syncthreads per step. Exchange: tag-in-data 8B pairs, sc0 sc1.

#define NGROUP  32
#define BATCH_G 32
#define T_STEPS 336
#define I_DIM   64
#define H_DIM   256
#define VSTRIDE 336   // ushorts per staged row: K=320 + 16 pad (672 B == 32 mod 128)
#define PAIRS   128   // h-pairs per batch row (256 cols / 2)
#define OUT_HALF 262144  // 1024*256

typedef __attribute__((ext_vector_type(8))) __bf16 bf16x8;
typedef __attribute__((ext_vector_type(8))) unsigned short ushort8_t;
typedef __attribute__((ext_vector_type(4))) float f32x4;
typedef __attribute__((ext_vector_type(4))) unsigned uint32x4;
typedef __attribute__((ext_vector_type(2))) unsigned uint32x2;

__device__ inline unsigned short f2bf(float f) {
  unsigned u = __builtin_bit_cast(unsigned, f);
  return (unsigned short)((u + 0x7fffu + ((u >> 16) & 1u)) >> 16);
}
__device__ inline float sigf(float x) { return 1.f / (1.f + __expf(-x)); }
__device__ inline float tanhfast(float x) { return 1.f - 2.f / (1.f + __expf(2.f * x)); }

// 4 concurrent coherent 16B loads (8 tagged pairs), one round trip.
__device__ inline void ld4_tagged(const uint32x2* p, uint32x4& a, uint32x4& b,
                                  uint32x4& c, uint32x4& d) {
  asm volatile(
      "global_load_dwordx4 %0, %4, off sc0 sc1\n\t"
      "global_load_dwordx4 %1, %5, off sc0 sc1\n\t"
      "global_load_dwordx4 %2, %6, off sc0 sc1\n\t"
      "global_load_dwordx4 %3, %7, off sc0 sc1\n\t"
      "s_waitcnt vmcnt(0)"
      : "=&v"(a), "=&v"(b), "=&v"(c), "=&v"(d)
      : "v"(p), "v"(p + 2), "v"(p + 4), "v"(p + 6)
      : "memory");
}
__device__ inline void st_pair(uint32x2* p, uint32x2 v) {
  asm volatile("global_store_dwordx2 %0, %1, off sc0 sc1" :: "v"(p), "v"(v) : "memory");
}

__global__ __launch_bounds__(512, 2) void lstm_persistent(
    const float* __restrict__ x, const float* __restrict__ W_ih,
    const float* __restrict__ W_hh, const float* __restrict__ b_ih,
    const float* __restrict__ b_hh, float* __restrict__ out,
    uint32x2* __restrict__ hbuf)
{
  __shared__ __align__(16) unsigned short v_lds[2][BATCH_G * VSTRIDE];

  const int tid  = threadIdx.x;
  const int gid  = blockIdx.x & 31;   // batch group
  const int mid  = blockIdx.x >> 5;   // member 0..7 (owns gate cols [mid*32, +32))
  const int wv   = tid >> 6;          // wave 0..7
  const int l    = tid & 63;
  const int l15  = l & 15, quad = l >> 4;
  const int rg   = wv >> 1;           // row-group 0..3: local cols [8*rg, +8)
  const int bh   = wv & 1;            // batch half: [16*bh, +16)

  // ---- A-fragments: local row r16 = 4*col_off + gate ----
  // Wave covers 2 row-tiles (rt): lane supplies A[m=l15][k=quad*8+e];
  // m = r16 -> gate = l15&3, col_off = l15>>2; col = rg*8 + rt*4 + col_off.
  bf16x8 afrag[2][10];
#pragma unroll
  for (int rt = 0; rt < 2; ++rt) {
    int grow = (l15 & 3) * H_DIM + mid * 32 + rg * 8 + rt * 4 + (l15 >> 2);
    const float* wih_row = W_ih + (long)grow * I_DIM;
    const float* whh_row = W_hh + (long)grow * H_DIM;
#pragma unroll
    for (int kt = 0; kt < 10; ++kt) {
      int kbase = kt * 32 + quad * 8;
      ushort8_t a;
#pragma unroll
      for (int e = 0; e < 8; ++e) {
        int k = kbase + e;
        float v = (k < I_DIM) ? wih_row[k] : whh_row[k - I_DIM];
        a[e] = f2bf(v);
      }
      afrag[rt][kt] = __builtin_bit_cast(bf16x8, a);
    }
  }

  // ---- bias as acc-init: D row = quad*4 + reg -> this lane's cell is
  // (col = rg*8 + rt*4 + quad, batch = bh*16 + l15); reg g = gate g. ----
  f32x4 bias[2];
#pragma unroll
  for (int rt = 0; rt < 2; ++rt) {
#pragma unroll
    for (int g = 0; g < 4; ++g) {
      int grow = g * H_DIM + mid * 32 + rg * 8 + rt * 4 + quad;
      bias[rt][g] = b_ih[grow] + b_hh[grow];
    }
  }

  const int batch = bh * 16 + l15;    // 0..31 within group
  float c_reg[2] = {0.f, 0.f};
  float h_keep[2];

  // ---- staging assignment: 512 threads cover 32 batch rows ----
  const int b_stage = tid >> 4;          // 0..31
  const int t15     = tid & 15;
  const int x_i4    = t15 * 4;           // 4 floats of x
  const int h_k     = t15 * 16;          // 16 bf16 of h
  const int pi_base = t15 * 8;           // 8 pairs
  const long xrow_base = ((long)(gid * 32 + b_stage)) * T_STEPS * I_DIM;

  // producer store: even-quad lanes store pair (col, col+1); pp = mid*16 + rg*4 + rt*2 + quad/2
  uint32x2* st_base = hbuf + ((long)gid * BATCH_G + batch) * PAIRS + mid * 16 + rg * 4 + (quad >> 1);
  const uint32x2* ld_src_base = hbuf + ((long)gid * BATCH_G + b_stage) * PAIRS + pi_base;
  const long buf_stride = (long)NGROUP * BATCH_G * PAIRS;

  for (int t = 1; t <= T_STEPS; ++t) {
    unsigned short* vbuf = v_lds[t & 1];

    // ---- issue x_t load early (overlaps the poll) ----
    const float4 xv = *(const float4*)(x + xrow_base + (long)(t - 1) * I_DIM + x_i4);

    // ---- stage x_t (fp32 -> bf16) ----
    {
      ushort4 xb;
      xb.x = f2bf(xv.x); xb.y = f2bf(xv.y); xb.z = f2bf(xv.z); xb.w = f2bf(xv.w);
      *(ushort4*)&vbuf[b_stage * VSTRIDE + x_i4] = xb;
    }

    // ---- stage h_{t-1}: poll the tagged data directly ----
    if (t > 1) {
      const unsigned tag = (unsigned)(t - 1);
      const uint32x2* hsrc = ld_src_base + ((t - 1) & 1) * buf_stride;
      uint32x4 A, Bv, C, D;
      int it = 0;
      for (;;) {
        ld4_tagged(hsrc, A, Bv, C, D);
        bool ok = (A[0] == tag) & (A[2] == tag) & (Bv[0] == tag) & (Bv[2] == tag) &
                  (C[0] == tag) & (C[2] == tag) & (D[0] == tag) & (D[2] == tag);
        if (ok) break;
        if (++it > (1 << 17)) break;   // safety valve vs. hang
      }
      uint32x4 e0, e1;
      e0[0] = A[1]; e0[1] = A[3]; e0[2] = Bv[1]; e0[3] = Bv[3];
      e1[0] = C[1]; e1[1] = C[3]; e1[2] = D[1];  e1[3] = D[3];
      *(uint32x4*)&vbuf[b_stage * VSTRIDE + I_DIM + h_k]     = e0;
      *(uint32x4*)&vbuf[b_stage * VSTRIDE + I_DIM + h_k + 8] = e1;
    } else {
      uint32x4 z = {0, 0, 0, 0};
      *(uint32x4*)&vbuf[b_stage * VSTRIDE + I_DIM + h_k]     = z;
      *(uint32x4*)&vbuf[b_stage * VSTRIDE + I_DIM + h_k + 8] = z;
    }
    __syncthreads();   // the ONLY barrier per step (v_lds double-buffered)

    // ---- MFMA: 2 row-tiles x 10 k-tiles, B shared across row-tiles ----
    f32x4 acc0 = bias[0], acc1 = bias[1];
    const unsigned short* vb = vbuf + (unsigned)batch * VSTRIDE + quad * 8;
#pragma unroll
    for (int kt = 0; kt < 10; ++kt) {
      bf16x8 bv = __builtin_bit_cast(bf16x8, *(const uint32x4*)(vb + kt * 32));
      acc0 = __builtin_amdgcn_mfma_f32_16x16x32_bf16(afrag[0][kt], bv, acc0, 0, 0, 0);
      acc1 = __builtin_amdgcn_mfma_f32_16x16x32_bf16(afrag[1][kt], bv, acc1, 0, 0, 0);
    }

    // ---- cell fully in registers; pack col-pair via shfl; store tagged ----
#pragma unroll
    for (int rt = 0; rt < 2; ++rt) {
      const f32x4 acc = rt ? acc1 : acc0;
      float c = sigf(acc[1]) * c_reg[rt] + sigf(acc[0]) * tanhfast(acc[2]);
      float h = sigf(acc[3]) * tanhfast(c);
      c_reg[rt] = c; h_keep[rt] = h;
      unsigned hb = (unsigned)f2bf(h);
      unsigned partner = (unsigned)__shfl_xor((int)hb, 16, 64);  // col^1, same batch
      if (!(quad & 1)) {
        uint32x2 pv;
        pv[0] = (unsigned)t;                  // tag
        pv[1] = hb | (partner << 16);         // (col, col+1)
        st_pair(st_base + rt * 2 + (t & 1) * buf_stride, pv);   // fire-and-forget
      }
    }
  }

  // ---- outputs: h_T then c_T, fp32 (pre-bf16-rounding values) ----
#pragma unroll
  for (int rt = 0; rt < 2; ++rt) {
    int gcol = mid * 32 + rg * 8 + rt * 4 + quad;
    long o = (long)(gid * BATCH_G + batch) * H_DIM + gcol;
    out[o]            = h_keep[rt];
    out[OUT_HALF + o] = c_reg[rt];
  }
}

extern "C" void kernel_launch(void* const* d_in, const int* in_sizes, int n_in,
                              void* d_out, int out_size, void* d_ws, size_t ws_size,
                              hipStream_t stream) {
  const float* x    = (const float*)d_in[0];
  const float* W_ih = (const float*)d_in[1];
  const float* W_hh = (const float*)d_in[2];
  const float* b_ih = (const float*)d_in[3];
  const float* b_hh = (const float*)d_in[4];
  float* out = (float*)d_out;

  uint32x2* hbuf = (uint32x2*)d_ws;   // 2 buffers x 32x32x128 pairs x 8 B = 2 MB

  // Clear tags so no stale value can match t in [1,336].
  hipMemsetAsync(d_ws, 0, 2u * NGROUP * BATCH_G * PAIRS * 8u, stream);
  lstm_persistent<<<dim3(256), dim3(512), 0, stream>>>(x, W_ih, W_hh, b_ih, b_hh, out, hbuf);
}

// Round 5
// 1000.276 us; speedup vs baseline: 1.3491x; 1.3491x over previous
//
#include <hip/hip_runtime.h>
#include <cstdint>

// LSTM: B=1024, T=336, I=64, H=256, gates 4H=1024, K = I+H = 320.
// 32 batch-groups x 8 member-WGs = 256 WGs (1/CU), persistent over all T.
// R5: R4's register-cell (gate-row remap r16 = 4*col + gate, cell fully in
// regs, bias as acc-init, one barrier/step) + pair-major exchange buffer
// hbuf[pair][batch] so producer stores are contiguous 128B runs (full
// sectors, no write amplification) and consumer threads load 64B aligned
// chunks. Wave `mid` never polls: its own slice short-cuts through LDS.

#define NGROUP  32
#define BATCH_G 32
#define T_STEPS 336
#define I_DIM   64
#define H_DIM   256
#define VSTRIDE 336   // ushorts per staged row: K=320 + 16 pad (16B-aligned rows)
#define PAIRS   128   // h-pairs per batch row (256 cols / 2)
#define OUT_HALF 262144  // 1024*256

typedef __attribute__((ext_vector_type(8))) __bf16 bf16x8;
typedef __attribute__((ext_vector_type(8))) unsigned short ushort8_t;
typedef __attribute__((ext_vector_type(4))) float f32x4;
typedef __attribute__((ext_vector_type(4))) unsigned uint32x4;
typedef __attribute__((ext_vector_type(2))) unsigned uint32x2;

__device__ inline unsigned short f2bf(float f) {
  unsigned u = __builtin_bit_cast(unsigned, f);
  return (unsigned short)((u + 0x7fffu + ((u >> 16) & 1u)) >> 16);
}
__device__ inline float sigf(float x) { return 1.f / (1.f + __expf(-x)); }
__device__ inline float tanhfast(float x) { return 1.f - 2.f / (1.f + __expf(2.f * x)); }

// 4 concurrent coherent 16B loads (8 tagged pairs = 64B contiguous), one round trip.
__device__ inline void ld4_tagged(const uint32x2* p, uint32x4& a, uint32x4& b,
                                  uint32x4& c, uint32x4& d) {
  asm volatile(
      "global_load_dwordx4 %0, %4, off sc0 sc1\n\t"
      "global_load_dwordx4 %1, %5, off sc0 sc1\n\t"
      "global_load_dwordx4 %2, %6, off sc0 sc1\n\t"
      "global_load_dwordx4 %3, %7, off sc0 sc1\n\t"
      "s_waitcnt vmcnt(0)"
      : "=&v"(a), "=&v"(b), "=&v"(c), "=&v"(d)
      : "v"(p), "v"(p + 2), "v"(p + 4), "v"(p + 6)
      : "memory");
}
__device__ inline void st_pair(uint32x2* p, uint32x2 v) {
  asm volatile("global_store_dwordx2 %0, %1, off sc0 sc1" :: "v"(p), "v"(v) : "memory");
}

__global__ __launch_bounds__(512, 2) void lstm_persistent(
    const float* __restrict__ x, const float* __restrict__ W_ih,
    const float* __restrict__ W_hh, const float* __restrict__ b_ih,
    const float* __restrict__ b_hh, float* __restrict__ out,
    uint32x2* __restrict__ hbuf)
{
  __shared__ __align__(16) unsigned short v_lds[2][BATCH_G * VSTRIDE];

  const int tid  = threadIdx.x;
  const int gid  = blockIdx.x & 31;   // batch group
  const int mid  = blockIdx.x >> 5;   // member 0..7 (owns gate cols [mid*32, +32))
  const int wv   = tid >> 6;          // wave 0..7
  const int l    = tid & 63;
  const int l15  = l & 15, quad = l >> 4;
  const int rg   = wv >> 1;           // row-group 0..3: local cols [8*rg, +8)
  const int bh   = wv & 1;            // batch half: [16*bh, +16)

  // ---- A-fragments: local row r16 = 4*col_off + gate ----
  bf16x8 afrag[2][10];
#pragma unroll
  for (int rt = 0; rt < 2; ++rt) {
    int grow = (l15 & 3) * H_DIM + mid * 32 + rg * 8 + rt * 4 + (l15 >> 2);
    const float* wih_row = W_ih + (long)grow * I_DIM;
    const float* whh_row = W_hh + (long)grow * H_DIM;
#pragma unroll
    for (int kt = 0; kt < 10; ++kt) {
      int kbase = kt * 32 + quad * 8;
      ushort8_t a;
#pragma unroll
      for (int e = 0; e < 8; ++e) {
        int k = kbase + e;
        float v = (k < I_DIM) ? wih_row[k] : whh_row[k - I_DIM];
        a[e] = f2bf(v);
      }
      afrag[rt][kt] = __builtin_bit_cast(bf16x8, a);
    }
  }

  // ---- bias as acc-init: lane's cell = (col = rg*8+rt*4+quad, batch = bh*16+l15) ----
  f32x4 bias[2];
#pragma unroll
  for (int rt = 0; rt < 2; ++rt) {
#pragma unroll
    for (int g = 0; g < 4; ++g) {
      int grow = g * H_DIM + mid * 32 + rg * 8 + rt * 4 + quad;
      bias[rt][g] = b_ih[grow] + b_hh[grow];
    }
  }

  const int batch = bh * 16 + l15;    // 0..31 within group
  float c_reg[2] = {0.f, 0.f};
  float h_keep[2];

  // ---- x staging: 16 threads per batch row ----
  const int b_stage = tid >> 4;          // 0..31
  const int x_i4    = (tid & 15) * 4;    // 4 floats of x
  const long xrow_base = ((long)(gid * 32 + b_stage)) * T_STEPS * I_DIM;

  // ---- h staging (consumer): thread owns pair p_ld, batches b0_ld..b0_ld+7
  //      = 64 B contiguous aligned in pair-major hbuf. Wave w covers pairs
  //      [16w, 16w+16) == member w's slice -> wave mid skips polling. ----
  const int p_ld  = tid >> 2;
  const int b0_ld = (tid & 3) * 8;
  const uint32x2* ld_base = hbuf + ((long)gid * PAIRS + p_ld) * BATCH_G + b0_ld;

  // ---- producer store: pair = mid*16 + rg*4 + rt*2 + (quad>>1), batch from l15
  //      -> lanes l15 contiguous => 128 B runs, full sectors. ----
  uint32x2* st_base = hbuf + ((long)gid * PAIRS + mid * 16 + rg * 4 + (quad >> 1)) * BATCH_G + batch;
  const long buf_stride = (long)NGROUP * PAIRS * BATCH_G;
  const bool own_wave = (wv == mid);

  for (int t = 1; t <= T_STEPS; ++t) {
    unsigned short* vbuf = v_lds[t & 1];

    // ---- issue x_t load early (overlaps the poll) ----
    const float4 xv = *(const float4*)(x + xrow_base + (long)(t - 1) * I_DIM + x_i4);
    {
      ushort4 xb;
      xb.x = f2bf(xv.x); xb.y = f2bf(xv.y); xb.z = f2bf(xv.z); xb.w = f2bf(xv.w);
      *(ushort4*)&vbuf[b_stage * VSTRIDE + x_i4] = xb;
    }

    // ---- stage h_{t-1} ----
    unsigned short* hdst = vbuf + b0_ld * VSTRIDE + I_DIM + 2 * p_ld;
    if (t > 1) {
      if (!own_wave) {   // own slice arrived via LDS from our cell lanes
        const unsigned tag = (unsigned)(t - 1);
        const uint32x2* hsrc = ld_base + ((t - 1) & 1) * buf_stride;
        uint32x4 A, Bv, C, D;
        int it = 0;
        for (;;) {
          ld4_tagged(hsrc, A, Bv, C, D);
          bool ok = (A[0] == tag) & (A[2] == tag) & (Bv[0] == tag) & (Bv[2] == tag) &
                    (C[0] == tag) & (C[2] == tag) & (D[0] == tag) & (D[2] == tag);
          if (ok) break;
          if (++it > (1 << 17)) break;   // safety valve vs. hang
          __builtin_amdgcn_s_sleep(1);
        }
        *(unsigned*)(hdst + 0 * VSTRIDE) = A[1];
        *(unsigned*)(hdst + 1 * VSTRIDE) = A[3];
        *(unsigned*)(hdst + 2 * VSTRIDE) = Bv[1];
        *(unsigned*)(hdst + 3 * VSTRIDE) = Bv[3];
        *(unsigned*)(hdst + 4 * VSTRIDE) = C[1];
        *(unsigned*)(hdst + 5 * VSTRIDE) = C[3];
        *(unsigned*)(hdst + 6 * VSTRIDE) = D[1];
        *(unsigned*)(hdst + 7 * VSTRIDE) = D[3];
      }
    } else {
      // t==1: h_0 = 0 for everyone (incl. own wave)
#pragma unroll
      for (int j = 0; j < 8; ++j) *(unsigned*)(hdst + j * VSTRIDE) = 0u;
    }
    __syncthreads();   // the ONLY barrier per step (v_lds double-buffered)

    // ---- MFMA: 2 row-tiles x 10 k-tiles, B shared across row-tiles ----
    f32x4 acc0 = bias[0], acc1 = bias[1];
    const unsigned short* vb = vbuf + (unsigned)batch * VSTRIDE + quad * 8;
#pragma unroll
    for (int kt = 0; kt < 10; ++kt) {
      bf16x8 bv = __builtin_bit_cast(bf16x8, *(const uint32x4*)(vb + kt * 32));
      acc0 = __builtin_amdgcn_mfma_f32_16x16x32_bf16(afrag[0][kt], bv, acc0, 0, 0, 0);
      acc1 = __builtin_amdgcn_mfma_f32_16x16x32_bf16(afrag[1][kt], bv, acc1, 0, 0, 0);
    }

    // ---- cell fully in registers; own-slice to LDS; tagged pair to global ----
    unsigned short* next_own = v_lds[(t + 1) & 1] + batch * VSTRIDE + I_DIM + mid * 32;
#pragma unroll
    for (int rt = 0; rt < 2; ++rt) {
      const f32x4 acc = rt ? acc1 : acc0;
      float c = sigf(acc[1]) * c_reg[rt] + sigf(acc[0]) * tanhfast(acc[2]);
      float h = sigf(acc[3]) * tanhfast(c);
      c_reg[rt] = c; h_keep[rt] = h;
      unsigned short hb16 = f2bf(h);
      next_own[rg * 8 + rt * 4 + quad] = hb16;                    // LDS shortcut (own WG)
      unsigned hb = (unsigned)hb16;
      unsigned partner = (unsigned)__shfl_xor((int)hb, 16, 64);   // col^1, same batch
      if (!(quad & 1)) {
        uint32x2 pv;
        pv[0] = (unsigned)t;                  // tag
        pv[1] = hb | (partner << 16);         // (col, col+1)
        st_pair(st_base + rt * 2 * BATCH_G + (t & 1) * buf_stride, pv);  // fire-and-forget
      }
    }
  }

  // ---- outputs: h_T then c_T, fp32 (pre-bf16-rounding values) ----
#pragma unroll
  for (int rt = 0; rt < 2; ++rt) {
    int gcol = mid * 32 + rg * 8 + rt * 4 + quad;
    long o = (long)(gid * BATCH_G + batch) * H_DIM + gcol;
    out[o]            = h_keep[rt];
    out[OUT_HALF + o] = c_reg[rt];
  }
}

extern "C" void kernel_launch(void* const* d_in, const int* in_sizes, int n_in,
                              void* d_out, int out_size, void* d_ws, size_t ws_size,
                              hipStream_t stream) {
  const float* x    = (const float*)d_in[0];
  const float* W_ih = (const float*)d_in[1];
  const float* W_hh = (const float*)d_in[2];
  const float* b_ih = (const float*)d_in[3];
  const float* b_hh = (const float*)d_in[4];
  float* out = (float*)d_out;

  uint32x2* hbuf = (uint32x2*)d_ws;   // 2 buffers x 32 groups x 128 pairs x 32 batch x 8 B = 2 MB

  // Clear tags so no stale value can match t in [1,336].
  hipMemsetAsync(d_ws, 0, 2u * NGROUP * PAIRS * BATCH_G * 8u, stream);
  lstm_persistent<<<dim3(256), dim3(512), 0, stream>>>(x, W_ih, W_hh, b_ih, b_hh, out, hbuf);
}